// Round 10
// baseline (113.682 us; speedup 1.0000x reference)
//
#include <hip/hip_runtime.h>
#include <math.h>

#define B 64
#define N 256
#define C 512

typedef float nfloat4 __attribute__((ext_vector_type(4)));

// guide modality for module m = 3*mi + j
__device__ __forceinline__ int guide_of(int m) {
    int mi = m / 3, j = m % 3;
    return (j == 0) ? mi : (j == 1 ? ((mi == 0) ? 1 : 0) : ((mi == 2) ? 1 : 2));
}

template<int NW>
__device__ __forceinline__ float breduce_sum(float v, volatile float* red, int t) {
    int w = t >> 6, l = t & 63;
#pragma unroll
    for (int mm = 1; mm < 64; mm <<= 1) v += __shfl_xor(v, mm);
    __syncthreads();
    if (l == 0) red[w] = v;
    __syncthreads();
    float s = red[0];
#pragma unroll
    for (int i = 1; i < NW; i++) s += red[i];
    return s;
}

template<int NW>
__device__ __forceinline__ float breduce_max(float v, volatile float* red, int t) {
    int w = t >> 6, l = t & 63;
#pragma unroll
    for (int mm = 1; mm < 64; mm <<= 1) v = fmaxf(v, __shfl_xor(v, mm));
    __syncthreads();
    if (l == 0) red[w] = v;
    __syncthreads();
    float s = red[0];
#pragma unroll
    for (int i = 1; i < NW; i++) s = fmaxf(s, red[i]);
    return s;
}

__device__ __forceinline__ float dot4(float4 a, float4 b) {
    return a.x * b.x + a.y * b.y + a.z * b.z + a.w * b.w;
}

// Fused: qproj partials (blocks 0..575) + mlp fc1 tiles (576..719) + gn (720..722)
// 4x4 register tiling: thread (t&15)=c-group, (t>>4)=b-group; 1 float4 W load +
// 4 LDS reads per 16 FMA.
__global__ __launch_bounds__(256) void k_proj_mlp(const float* g0, const float* g1, const float* g2,
                                                  const float* qw, const float* w1,
                                                  float* part, float* h1part, float* gn) {
    int bid = blockIdx.x;
    int t = threadIdx.x;
    __shared__ float gt[64 * 132];  // padded stride 132: bank (4b+e)%32, conflict-free
    if (bid < 576) {
        int cx = bid & 7, m = (bid >> 3) % 9, ks = bid / 72;
        int e0 = ks * 64;
        int gi = guide_of(m);
        const float* g = (gi == 0) ? g0 : (gi == 1 ? g1 : g2);
        for (int idx = t; idx < 1024; idx += 256) {
            int r = idx >> 4, c4 = idx & 15;
            ((float4*)&gt[r * 132])[c4] = ((const float4*)(g + (size_t)r * C + e0))[c4];
        }
        __syncthreads();
        int c0 = cx * 64 + 4 * (t & 15);
        int b0 = 4 * (t >> 4);
        float4 acc[4];
#pragma unroll
        for (int j = 0; j < 4; j++) acc[j] = make_float4(0.f, 0.f, 0.f, 0.f);
        const float* W = qw + (size_t)m * C * C + (size_t)e0 * C + c0;
#pragma unroll 4
        for (int e = 0; e < 64; e++) {
            float4 wv = *(const float4*)(W + (size_t)e * C);
#pragma unroll
            for (int j = 0; j < 4; j++) {
                float gv = gt[(b0 + j) * 132 + e];
                acc[j].x += gv * wv.x; acc[j].y += gv * wv.y;
                acc[j].z += gv * wv.z; acc[j].w += gv * wv.w;
            }
        }
#pragma unroll
        for (int j = 0; j < 4; j++)
            *(float4*)(part + (size_t)ks * 294912 + ((size_t)m * B + b0 + j) * C + c0) = acc[j];
    } else if (bid < 720) {
        int r = bid - 576;  // 0..143 : (cx=4, mi=3, ks=12)
        int cx = r & 3, mi = (r >> 2) % 3, ks = r / 12;
        int e0 = ks * 128;
        const float* g = (e0 < 512) ? g0 : (e0 < 1024 ? g1 : g2);
        int eo = e0 & 511;
        for (int idx = t; idx < 2048; idx += 256) {
            int rr = idx >> 5, c4 = idx & 31;
            ((float4*)&gt[rr * 132])[c4] = ((const float4*)(g + (size_t)rr * C + eo))[c4];
        }
        __syncthreads();
        int c0 = cx * 64 + 4 * (t & 15);
        int b0 = 4 * (t >> 4);
        float4 acc[4];
#pragma unroll
        for (int j = 0; j < 4; j++) acc[j] = make_float4(0.f, 0.f, 0.f, 0.f);
        const float* W = w1 + ((size_t)mi * 1536 + e0) * 256 + c0;
#pragma unroll 4
        for (int e = 0; e < 128; e++) {
            float4 wv = *(const float4*)(W + (size_t)e * 256);
#pragma unroll
            for (int j = 0; j < 4; j++) {
                float gv = gt[(b0 + j) * 132 + e];
                acc[j].x += gv * wv.x; acc[j].y += gv * wv.y;
                acc[j].z += gv * wv.z; acc[j].w += gv * wv.w;
            }
        }
#pragma unroll
        for (int j = 0; j < 4; j++)
            *(float4*)(h1part + (((size_t)ks * 3 + mi) * B + b0 + j) * 256 + c0) = acc[j];
    } else {
        int gm = bid - 720;  // 0..2
        const float* g = (gm == 0) ? g0 : (gm == 1 ? g1 : g2);
        int wv = t >> 6, l = t & 63;
        for (int r = wv; r < 64; r += 4) {
            const float4* gv = (const float4*)(g + (size_t)r * C);
            float4 a = gv[l], b2 = gv[64 + l];
            float n2 = dot4(a, a) + dot4(b2, b2);
#pragma unroll
            for (int mm = 1; mm < 64; mm <<= 1) n2 += __shfl_xor(n2, mm);
            float inv = 1.0f / fmaxf(sqrtf(n2), 1e-8f);
            float4* o = (float4*)(gn + ((size_t)gm * B + r) * C);
            a.x *= inv; a.y *= inv; a.z *= inv; a.w *= inv;
            b2.x *= inv; b2.y *= inv; b2.z *= inv; b2.w *= inv;
            o[l] = a; o[64 + l] = b2;
        }
    }
}

// kpart[ds][m][b][c] = sum_{d in slice ds} kw[m,c,d] * q[m,b,d]
// q inline-reduced from part; qkb_part by cx==0 blocks. 4x4 register tiling.
__global__ __launch_bounds__(256) void k_kproj(const float* kw, const float* part,
                                               const float* qb, const float* kb,
                                               float* kpart, float* qkb_part) {
    int cx = blockIdx.x, m = blockIdx.y, ds = blockIdx.z;
    int t = threadIdx.x;
    int c0b = cx * 64, d0 = ds * 64;
    __shared__ float kt[64][65];  // [c][d] padded: bank (c+d)%32
    __shared__ float qt[64][65];  // [b][d] padded
    for (int idx = t; idx < 1024; idx += 256) {
        int r = idx >> 4, c4 = idx & 15;
        float4 kv4 = *(const float4*)(kw + ((size_t)m * C + c0b + r) * C + d0 + c4 * 4);
        kt[r][c4 * 4 + 0] = kv4.x; kt[r][c4 * 4 + 1] = kv4.y;
        kt[r][c4 * 4 + 2] = kv4.z; kt[r][c4 * 4 + 3] = kv4.w;
        float4 s = *(const float4*)(qb + (size_t)m * C + d0 + c4 * 4);
        const float* pp = part + ((size_t)m * B + r) * C + d0 + c4 * 4;
#pragma unroll
        for (int ks = 0; ks < 8; ks++) {
            float4 v = *(const float4*)(pp + (size_t)ks * 294912);
            s.x += v.x; s.y += v.y; s.z += v.z; s.w += v.w;
        }
        qt[r][c4 * 4 + 0] = s.x; qt[r][c4 * 4 + 1] = s.y;
        qt[r][c4 * 4 + 2] = s.z; qt[r][c4 * 4 + 3] = s.w;
    }
    __syncthreads();
    int c0 = 4 * (t & 15);
    int b0 = 4 * (t >> 4);
    float4 acc[4];
#pragma unroll
    for (int j = 0; j < 4; j++) acc[j] = make_float4(0.f, 0.f, 0.f, 0.f);
#pragma unroll 4
    for (int d = 0; d < 64; d++) {
        float k0 = kt[c0 + 0][d], k1 = kt[c0 + 1][d], k2 = kt[c0 + 2][d], k3 = kt[c0 + 3][d];
#pragma unroll
        for (int j = 0; j < 4; j++) {
            float qv = qt[b0 + j][d];
            acc[j].x += qv * k0; acc[j].y += qv * k1;
            acc[j].z += qv * k2; acc[j].w += qv * k3;
        }
    }
#pragma unroll
    for (int j = 0; j < 4; j++)
        *(float4*)(kpart + (size_t)ds * 294912 + ((size_t)m * B + b0 + j) * C + c0b + c0) = acc[j];
    if (cx == 0 && t < 64) {
        float s = 0.f;
        const float* kbp = kb + (size_t)m * C + d0;
        for (int d = 0; d < 64; d++) s += qt[t][d] * kbp[d];
        qkb_part[((size_t)m * 8 + ds) * B + t] = s;
    }
}

// logits: grid (B, 3, 8) x 256; 32 tokens/block; 8 lanes/token; gn precomputed.
__global__ __launch_bounds__(256) void k_logits(const float* p0, const float* p1, const float* p2,
                                                const float* kpart, const float* qkb_part,
                                                const float* gn, float* lgt) {
    int b = blockIdx.x, mi = blockIdx.y, ns = blockIdx.z;
    int t = threadIdx.x, w = t >> 6, l = t & 63;
    const float* p = (mi == 0) ? p0 : (mi == 1 ? p1 : p2);
    __shared__ float q6[6][512];
    __shared__ float qkb_s[3];
    for (int idx = t; idx < 768; idx += 256) {
        int row = idx >> 7, c4 = idx & 127;
        float4 v;
        if (row < 3) {
            int m = 3 * mi + row;
            const float4* kp = (const float4*)kpart + ((size_t)m * B + b) * 128 + c4;
            v = kp[0];
#pragma unroll
            for (int ds = 1; ds < 8; ds++) {
                float4 u = kp[(size_t)ds * 73728];
                v.x += u.x; v.y += u.y; v.z += u.z; v.w += u.w;
            }
        } else {
            int gi = guide_of(3 * mi + row - 3);
            v = ((const float4*)(gn + ((size_t)gi * B + b) * C))[c4];
        }
        ((float4*)q6[row])[c4] = v;
    }
    if (t < 3) {
        int m = 3 * mi + t;
        float s = 0.f;
#pragma unroll
        for (int ds = 0; ds < 8; ds++) s += qkb_part[((size_t)m * 8 + ds) * B + b];
        qkb_s[t] = s;
    }
    __syncthreads();
    float qkbv[3];
#pragma unroll
    for (int j = 0; j < 3; j++) qkbv[j] = qkb_s[j];
    const float4* pbase = (const float4*)(p + (size_t)b * N * C);
    const float SCALE = 0.044194173824159216f;  // 512^-0.5
    float* L = lgt + (size_t)(mi * B + b) * 3 * N;
    int s = l & 7, tl = l >> 3;
    const float4* Q0 = (const float4*)q6[0];
    const float4* Q1 = (const float4*)q6[1];
    const float4* Q2 = (const float4*)q6[2];
    const float4* G0 = (const float4*)q6[3];
    const float4* G1 = (const float4*)q6[4];
    const float4* G2 = (const float4*)q6[5];
    {
        int n = ns * 32 + w * 8 + tl;
        const float4* prow = pbase + (size_t)n * 128;
        float pp = 0.f, dj0 = 0.f, dj1 = 0.f, dj2 = 0.f, cj0 = 0.f, cj1 = 0.f, cj2 = 0.f;
#pragma unroll
        for (int i = 0; i < 16; i++) {
            int o = s + 8 * i;
            float4 pv = prow[o];
            pp  += dot4(pv, pv);
            dj0 += dot4(pv, Q0[o]);
            dj1 += dot4(pv, Q1[o]);
            dj2 += dot4(pv, Q2[o]);
            cj0 += dot4(pv, G0[o]);
            cj1 += dot4(pv, G1[o]);
            cj2 += dot4(pv, G2[o]);
        }
#pragma unroll
        for (int mm = 1; mm < 8; mm <<= 1) {
            pp  += __shfl_xor(pp, mm);
            dj0 += __shfl_xor(dj0, mm);
            dj1 += __shfl_xor(dj1, mm);
            dj2 += __shfl_xor(dj2, mm);
            cj0 += __shfl_xor(cj0, mm);
            cj1 += __shfl_xor(cj1, mm);
            cj2 += __shfl_xor(cj2, mm);
        }
        if (s == 0) {
            float rn = fmaxf(sqrtf(pp), 1e-8f);
            float ic = 1.0f / (rn * 0.3f);
            L[0 * N + n] = (dj0 + qkbv[0]) * SCALE + cj0 * ic;
            L[1 * N + n] = (dj1 + qkbv[1]) * SCALE + cj1 * ic;
            L[2 * N + n] = (dj2 + qkbv[2]) * SCALE + cj2 * ic;
        }
    }
}

// finscale: grid (B, 3, 8) x 256, blockIdx REVERSED -> consume L3 tail first
// (k_logits read patches in forward order; the last ~256MB are L3-resident, so
// reading in reverse turns the 100MB HBM re-read into mostly L3 hits).
// Redundant MLP+score+quantile per block (identical fp order -> identical thr),
// then 32-token slab rescale.
__global__ __launch_bounds__(256) void k_finscale(const float* lgt, const float* h1part,
                                                  const float* b1, const float* lng, const float* lnb,
                                                  const float* w2, const float* b2,
                                                  const float* w3, const float* b3,
                                                  const float* p0, const float* p1, const float* p2,
                                                  float* out) {
    int b = (B - 1) - blockIdx.x;
    int mi = 2 - blockIdx.y;
    int ns = 7 - blockIdx.z;
    int t = threadIdx.x;
    __shared__ float h1[256];
    __shared__ float h2p[4][64];
    __shared__ float h2[64];
    __shared__ float red[4];
    __shared__ float wjs[3];
    __shared__ float sc[256];
    __shared__ float mks[256];
    __shared__ float thr_s;
    // --- MLP phase ---
    float a1 = b1[mi * 256 + t];
#pragma unroll
    for (int ks = 0; ks < 12; ks++) a1 += h1part[(((size_t)ks * 3 + mi) * B + b) * 256 + t];
    float total = breduce_sum<4>(a1, red, t);
    float mean = total * (1.0f / 256.0f);
    float dv = a1 - mean;
    float vtot = breduce_sum<4>(dv * dv, red, t);
    float var = vtot * (1.0f / 256.0f);
    float x = dv / sqrtf(var + 1e-5f) * lng[mi * 256 + t] + lnb[mi * 256 + t];
    x = 0.5f * x * (1.0f + erff(x * 0.70710678118654752f));
    h1[t] = x;
    __syncthreads();
    {
        int col = t & 63, sl = t >> 6;  // 4 slices of 64
        float a2 = 0.f;
        const float* W2 = w2 + (size_t)mi * 256 * 64 + col;
#pragma unroll 8
        for (int e = sl * 64; e < sl * 64 + 64; e++) a2 += h1[e] * W2[(size_t)e * 64];
        h2p[sl][col] = a2;
    }
    __syncthreads();
    if (t < 64) {
        float a2 = b2[mi * 64 + t];
#pragma unroll
        for (int s2 = 0; s2 < 4; s2++) a2 += h2p[s2][t];
        a2 = 0.5f * a2 * (1.0f + erff(a2 * 0.70710678118654752f));
        h2[t] = a2;
    }
    __syncthreads();
    if (t == 0) {
        float l3[3];
        for (int j = 0; j < 3; j++) {
            float a3 = b3[mi * 3 + j];
            for (int e = 0; e < 64; e++) a3 += h2[e] * w3[((size_t)mi * 64 + e) * 3 + j];
            l3[j] = a3;
        }
        float mx = fmaxf(l3[0], fmaxf(l3[1], l3[2]));
        float e0 = expf(l3[0] - mx), e1 = expf(l3[1] - mx), e2 = expf(l3[2] - mx);
        float inv = 1.0f / (e0 + e1 + e2);
        wjs[0] = e0 * inv; wjs[1] = e1 * inv; wjs[2] = e2 * inv;
    }
    __syncthreads();
    // --- score phase ---
    const float* L = lgt + (size_t)(mi * B + b) * 3 * N;
    float score = 0.f;
    for (int j = 0; j < 3; j++) {
        float v = L[j * N + t];
        float mx = breduce_max<4>(v, red, t);
        float e = expf(v - mx);
        float s = breduce_sum<4>(e, red, t);
        float pr = e / s;
        float tot2 = breduce_sum<4>(pr, red, t);
        float mean2 = tot2 * (1.0f / 256.0f);
        float dv2 = pr - mean2;
        float vtot2 = breduce_sum<4>(dv2 * dv2, red, t);
        float sd = sqrtf(vtot2 * (1.0f / 255.0f)) + 1e-5f;
        float z = dv2 / sd;
        float sg = 1.0f / (1.0f + expf(-z));
        score += wjs[j] * sg;
    }
    sc[t] = score;
    __syncthreads();
    {
        int cl = 0, ce = 0;
        for (int m2 = 0; m2 < N; m2++) {
            float v2 = sc[m2];
            cl += (v2 < score) ? 1 : 0;
            ce += (v2 == score) ? 1 : 0;
        }
        if (cl <= 102 && 102 < cl + ce) thr_s = score;
    }
    __syncthreads();
    float thr = thr_s;
    float mk = 1.0f / (1.0f + expf(-(score - thr) * (1.0f / 0.3f)));
    mks[t] = mk;
    if ((t >> 5) == ns)
        out[(size_t)3 * B * N * C + ((size_t)mi * B + b) * N + t] = mk;
    __syncthreads();
    // --- scale phase: 32 tokens (ns*32..), 4096 float4 ---
    const float* p = (mi == 0) ? p0 : (mi == 1 ? p1 : p2);
    const nfloat4* pslab = (const nfloat4*)(p + (size_t)b * N * C + (size_t)ns * 32 * C);
    nfloat4* oslab = (nfloat4*)(out + (size_t)mi * B * N * C + (size_t)b * N * C
                                + (size_t)ns * 32 * C);
#pragma unroll 4
    for (int idx = t; idx < 4096; idx += 256) {
        nfloat4 v = __builtin_nontemporal_load(pslab + idx);
        float mkv = mks[ns * 32 + (idx >> 7)];
        v.x *= mkv; v.y *= mkv; v.z *= mkv; v.w *= mkv;
        __builtin_nontemporal_store(v, oslab + idx);
    }
}

extern "C" void kernel_launch(void* const* d_in, const int* in_sizes, int n_in,
                              void* d_out, int out_size, void* d_ws, size_t ws_size,
                              hipStream_t stream) {
    const float* rgb   = (const float*)d_in[0];
    const float* nir   = (const float*)d_in[1];
    const float* tir   = (const float*)d_in[2];
    const float* rgb_g = (const float*)d_in[3];
    const float* nir_g = (const float*)d_in[4];
    const float* tir_g = (const float*)d_in[5];
    const float* attn_qw = (const float*)d_in[6];
    const float* attn_qb = (const float*)d_in[7];
    const float* attn_kw = (const float*)d_in[8];
    const float* attn_kb = (const float*)d_in[9];
    const float* mlp_w1 = (const float*)d_in[10];
    const float* mlp_b1 = (const float*)d_in[11];
    const float* ln_g = (const float*)d_in[12];
    const float* ln_b = (const float*)d_in[13];
    const float* mlp_w2 = (const float*)d_in[14];
    const float* mlp_b2 = (const float*)d_in[15];
    const float* mlp_w3 = (const float*)d_in[16];
    const float* mlp_b3 = (const float*)d_in[17];
    float* out = (float*)d_out;

    float* ws = (float*)d_ws;
    // layout (floats):
    float* part     = ws;                // 8*294912 = 2359296
    float* kpart    = ws + 2359296;      // 2359296
    float* qkb_part = ws + 4718592;      // 9*8*64 = 4608 -> pad 5120
    float* h1part   = ws + 4723712;      // 12*3*64*256 = 589824
    float* lgt      = ws + 5313536;      // 3*64*3*256 = 147456
    float* gn       = ws + 5460992;      // 3*64*512 = 98304
    // total 5559296 floats = 22.2 MB

    k_proj_mlp<<<723, 256, 0, stream>>>(rgb_g, nir_g, tir_g, attn_qw, mlp_w1,
                                        part, h1part, gn);
    k_kproj<<<dim3(8, 9, 8), 256, 0, stream>>>(attn_kw, part, attn_qb, attn_kb,
                                               kpart, qkb_part);
    k_logits<<<dim3(B, 3, 8), 256, 0, stream>>>(rgb, nir, tir, kpart, qkb_part, gn, lgt);
    k_finscale<<<dim3(B, 3, 8), 256, 0, stream>>>(lgt, h1part, mlp_b1, ln_g, ln_b,
                                                  mlp_w2, mlp_b2, mlp_w3, mlp_b3,
                                                  rgb, nir, tir, out);
}

// Round 11
// 106.366 us; speedup vs baseline: 1.0688x; 1.0688x over previous
//
#include <hip/hip_runtime.h>
#include <math.h>

#define B 64
#define N 256
#define C 512

typedef float nfloat4 __attribute__((ext_vector_type(4)));

// guide modality for module m = 3*mi + j
__device__ __forceinline__ int guide_of(int m) {
    int mi = m / 3, j = m % 3;
    return (j == 0) ? mi : (j == 1 ? ((mi == 0) ? 1 : 0) : ((mi == 2) ? 1 : 2));
}

template<int NW>
__device__ __forceinline__ float breduce_sum(float v, volatile float* red, int t) {
    int w = t >> 6, l = t & 63;
#pragma unroll
    for (int mm = 1; mm < 64; mm <<= 1) v += __shfl_xor(v, mm);
    __syncthreads();
    if (l == 0) red[w] = v;
    __syncthreads();
    float s = red[0];
#pragma unroll
    for (int i = 1; i < NW; i++) s += red[i];
    return s;
}

template<int NW>
__device__ __forceinline__ float breduce_max(float v, volatile float* red, int t) {
    int w = t >> 6, l = t & 63;
#pragma unroll
    for (int mm = 1; mm < 64; mm <<= 1) v = fmaxf(v, __shfl_xor(v, mm));
    __syncthreads();
    if (l == 0) red[w] = v;
    __syncthreads();
    float s = red[0];
#pragma unroll
    for (int i = 1; i < NW; i++) s = fmaxf(s, red[i]);
    return s;
}

__device__ __forceinline__ float dot4(float4 a, float4 b) {
    return a.x * b.x + a.y * b.y + a.z * b.z + a.w * b.w;
}

// Fused: qproj partials (blocks 0..575) + mlp fc1 tiles (576..719) + gn (720..722)
// 4x4 register tiling: thread (t&15)=c-group, (t>>4)=b-group; 1 float4 W load +
// 4 LDS reads per 16 FMA.
__global__ __launch_bounds__(256) void k_proj_mlp(const float* g0, const float* g1, const float* g2,
                                                  const float* qw, const float* w1,
                                                  float* part, float* h1part, float* gn) {
    int bid = blockIdx.x;
    int t = threadIdx.x;
    __shared__ float gt[64 * 132];  // padded stride 132: bank (4b+e)%32, conflict-free
    if (bid < 576) {
        int cx = bid & 7, m = (bid >> 3) % 9, ks = bid / 72;
        int e0 = ks * 64;
        int gi = guide_of(m);
        const float* g = (gi == 0) ? g0 : (gi == 1 ? g1 : g2);
        for (int idx = t; idx < 1024; idx += 256) {
            int r = idx >> 4, c4 = idx & 15;
            ((float4*)&gt[r * 132])[c4] = ((const float4*)(g + (size_t)r * C + e0))[c4];
        }
        __syncthreads();
        int c0 = cx * 64 + 4 * (t & 15);
        int b0 = 4 * (t >> 4);
        float4 acc[4];
#pragma unroll
        for (int j = 0; j < 4; j++) acc[j] = make_float4(0.f, 0.f, 0.f, 0.f);
        const float* W = qw + (size_t)m * C * C + (size_t)e0 * C + c0;
#pragma unroll 4
        for (int e = 0; e < 64; e++) {
            float4 wv = *(const float4*)(W + (size_t)e * C);
#pragma unroll
            for (int j = 0; j < 4; j++) {
                float gv = gt[(b0 + j) * 132 + e];
                acc[j].x += gv * wv.x; acc[j].y += gv * wv.y;
                acc[j].z += gv * wv.z; acc[j].w += gv * wv.w;
            }
        }
#pragma unroll
        for (int j = 0; j < 4; j++)
            *(float4*)(part + (size_t)ks * 294912 + ((size_t)m * B + b0 + j) * C + c0) = acc[j];
    } else if (bid < 720) {
        int r = bid - 576;  // 0..143 : (cx=4, mi=3, ks=12)
        int cx = r & 3, mi = (r >> 2) % 3, ks = r / 12;
        int e0 = ks * 128;
        const float* g = (e0 < 512) ? g0 : (e0 < 1024 ? g1 : g2);
        int eo = e0 & 511;
        for (int idx = t; idx < 2048; idx += 256) {
            int rr = idx >> 5, c4 = idx & 31;
            ((float4*)&gt[rr * 132])[c4] = ((const float4*)(g + (size_t)rr * C + eo))[c4];
        }
        __syncthreads();
        int c0 = cx * 64 + 4 * (t & 15);
        int b0 = 4 * (t >> 4);
        float4 acc[4];
#pragma unroll
        for (int j = 0; j < 4; j++) acc[j] = make_float4(0.f, 0.f, 0.f, 0.f);
        const float* W = w1 + ((size_t)mi * 1536 + e0) * 256 + c0;
#pragma unroll 4
        for (int e = 0; e < 128; e++) {
            float4 wv = *(const float4*)(W + (size_t)e * 256);
#pragma unroll
            for (int j = 0; j < 4; j++) {
                float gv = gt[(b0 + j) * 132 + e];
                acc[j].x += gv * wv.x; acc[j].y += gv * wv.y;
                acc[j].z += gv * wv.z; acc[j].w += gv * wv.w;
            }
        }
#pragma unroll
        for (int j = 0; j < 4; j++)
            *(float4*)(h1part + (((size_t)ks * 3 + mi) * B + b0 + j) * 256 + c0) = acc[j];
    } else {
        int gm = bid - 720;  // 0..2
        const float* g = (gm == 0) ? g0 : (gm == 1 ? g1 : g2);
        int wv = t >> 6, l = t & 63;
        for (int r = wv; r < 64; r += 4) {
            const float4* gv = (const float4*)(g + (size_t)r * C);
            float4 a = gv[l], b2 = gv[64 + l];
            float n2 = dot4(a, a) + dot4(b2, b2);
#pragma unroll
            for (int mm = 1; mm < 64; mm <<= 1) n2 += __shfl_xor(n2, mm);
            float inv = 1.0f / fmaxf(sqrtf(n2), 1e-8f);
            float4* o = (float4*)(gn + ((size_t)gm * B + r) * C);
            a.x *= inv; a.y *= inv; a.z *= inv; a.w *= inv;
            b2.x *= inv; b2.y *= inv; b2.z *= inv; b2.w *= inv;
            o[l] = a; o[64 + l] = b2;
        }
    }
}

// kpart[ds][m][b][c] = sum_{d in slice ds} kw[m,c,d] * q[m,b,d]
// q inline-reduced from part; qkb_part by cx==0 blocks. 4x4 register tiling.
__global__ __launch_bounds__(256) void k_kproj(const float* kw, const float* part,
                                               const float* qb, const float* kb,
                                               float* kpart, float* qkb_part) {
    int cx = blockIdx.x, m = blockIdx.y, ds = blockIdx.z;
    int t = threadIdx.x;
    int c0b = cx * 64, d0 = ds * 64;
    __shared__ float kt[64][65];  // [c][d] padded: bank (c+d)%32
    __shared__ float qt[64][65];  // [b][d] padded
    for (int idx = t; idx < 1024; idx += 256) {
        int r = idx >> 4, c4 = idx & 15;
        float4 kv4 = *(const float4*)(kw + ((size_t)m * C + c0b + r) * C + d0 + c4 * 4);
        kt[r][c4 * 4 + 0] = kv4.x; kt[r][c4 * 4 + 1] = kv4.y;
        kt[r][c4 * 4 + 2] = kv4.z; kt[r][c4 * 4 + 3] = kv4.w;
        float4 s = *(const float4*)(qb + (size_t)m * C + d0 + c4 * 4);
        const float* pp = part + ((size_t)m * B + r) * C + d0 + c4 * 4;
#pragma unroll
        for (int ks = 0; ks < 8; ks++) {
            float4 v = *(const float4*)(pp + (size_t)ks * 294912);
            s.x += v.x; s.y += v.y; s.z += v.z; s.w += v.w;
        }
        qt[r][c4 * 4 + 0] = s.x; qt[r][c4 * 4 + 1] = s.y;
        qt[r][c4 * 4 + 2] = s.z; qt[r][c4 * 4 + 3] = s.w;
    }
    __syncthreads();
    int c0 = 4 * (t & 15);
    int b0 = 4 * (t >> 4);
    float4 acc[4];
#pragma unroll
    for (int j = 0; j < 4; j++) acc[j] = make_float4(0.f, 0.f, 0.f, 0.f);
#pragma unroll 4
    for (int d = 0; d < 64; d++) {
        float k0 = kt[c0 + 0][d], k1 = kt[c0 + 1][d], k2 = kt[c0 + 2][d], k3 = kt[c0 + 3][d];
#pragma unroll
        for (int j = 0; j < 4; j++) {
            float qv = qt[b0 + j][d];
            acc[j].x += qv * k0; acc[j].y += qv * k1;
            acc[j].z += qv * k2; acc[j].w += qv * k3;
        }
    }
#pragma unroll
    for (int j = 0; j < 4; j++)
        *(float4*)(kpart + (size_t)ds * 294912 + ((size_t)m * B + b0 + j) * C + c0b + c0) = acc[j];
    if (cx == 0 && t < 64) {
        float s = 0.f;
        const float* kbp = kb + (size_t)m * C + d0;
        for (int d = 0; d < 64; d++) s += qt[t][d] * kbp[d];
        qkb_part[((size_t)m * 8 + ds) * B + t] = s;
    }
}

// logits: grid (B, 3, 8) x 256; 32 tokens/block; 8 lanes/token; gn precomputed.
__global__ __launch_bounds__(256) void k_logits(const float* p0, const float* p1, const float* p2,
                                                const float* kpart, const float* qkb_part,
                                                const float* gn, float* lgt) {
    int b = blockIdx.x, mi = blockIdx.y, ns = blockIdx.z;
    int t = threadIdx.x, w = t >> 6, l = t & 63;
    const float* p = (mi == 0) ? p0 : (mi == 1 ? p1 : p2);
    __shared__ float q6[6][512];
    __shared__ float qkb_s[3];
    for (int idx = t; idx < 768; idx += 256) {
        int row = idx >> 7, c4 = idx & 127;
        float4 v;
        if (row < 3) {
            int m = 3 * mi + row;
            const float4* kp = (const float4*)kpart + ((size_t)m * B + b) * 128 + c4;
            v = kp[0];
#pragma unroll
            for (int ds = 1; ds < 8; ds++) {
                float4 u = kp[(size_t)ds * 73728];
                v.x += u.x; v.y += u.y; v.z += u.z; v.w += u.w;
            }
        } else {
            int gi = guide_of(3 * mi + row - 3);
            v = ((const float4*)(gn + ((size_t)gi * B + b) * C))[c4];
        }
        ((float4*)q6[row])[c4] = v;
    }
    if (t < 3) {
        int m = 3 * mi + t;
        float s = 0.f;
#pragma unroll
        for (int ds = 0; ds < 8; ds++) s += qkb_part[((size_t)m * 8 + ds) * B + b];
        qkb_s[t] = s;
    }
    __syncthreads();
    float qkbv[3];
#pragma unroll
    for (int j = 0; j < 3; j++) qkbv[j] = qkb_s[j];
    const float4* pbase = (const float4*)(p + (size_t)b * N * C);
    const float SCALE = 0.044194173824159216f;  // 512^-0.5
    float* L = lgt + (size_t)(mi * B + b) * 3 * N;
    int s = l & 7, tl = l >> 3;
    const float4* Q0 = (const float4*)q6[0];
    const float4* Q1 = (const float4*)q6[1];
    const float4* Q2 = (const float4*)q6[2];
    const float4* G0 = (const float4*)q6[3];
    const float4* G1 = (const float4*)q6[4];
    const float4* G2 = (const float4*)q6[5];
    {
        int n = ns * 32 + w * 8 + tl;
        const float4* prow = pbase + (size_t)n * 128;
        float pp = 0.f, dj0 = 0.f, dj1 = 0.f, dj2 = 0.f, cj0 = 0.f, cj1 = 0.f, cj2 = 0.f;
#pragma unroll
        for (int i = 0; i < 16; i++) {
            int o = s + 8 * i;
            float4 pv = prow[o];
            pp  += dot4(pv, pv);
            dj0 += dot4(pv, Q0[o]);
            dj1 += dot4(pv, Q1[o]);
            dj2 += dot4(pv, Q2[o]);
            cj0 += dot4(pv, G0[o]);
            cj1 += dot4(pv, G1[o]);
            cj2 += dot4(pv, G2[o]);
        }
#pragma unroll
        for (int mm = 1; mm < 8; mm <<= 1) {
            pp  += __shfl_xor(pp, mm);
            dj0 += __shfl_xor(dj0, mm);
            dj1 += __shfl_xor(dj1, mm);
            dj2 += __shfl_xor(dj2, mm);
            cj0 += __shfl_xor(cj0, mm);
            cj1 += __shfl_xor(cj1, mm);
            cj2 += __shfl_xor(cj2, mm);
        }
        if (s == 0) {
            float rn = fmaxf(sqrtf(pp), 1e-8f);
            float ic = 1.0f / (rn * 0.3f);
            L[0 * N + n] = (dj0 + qkbv[0]) * SCALE + cj0 * ic;
            L[1 * N + n] = (dj1 + qkbv[1]) * SCALE + cj1 * ic;
            L[2 * N + n] = (dj2 + qkbv[2]) * SCALE + cj2 * ic;
        }
    }
}

// finscale: grid (B, 3, 8) x 256, forward order. The 32-token patch-slab fetch
// is ISSUED FIRST (8 float4/thread into registers, plain cached loads) so the
// memory system streams it while the redundant MLP+score+quantile prologue
// computes (vmcnt is in-order: every later load-wait drains these at full BW).
// Remaining 8 float4/thread are streamed in the store phase. NT stores only.
__global__ __launch_bounds__(256) void k_finscale(const float* lgt, const float* h1part,
                                                  const float* b1, const float* lng, const float* lnb,
                                                  const float* w2, const float* b2,
                                                  const float* w3, const float* b3,
                                                  const float* p0, const float* p1, const float* p2,
                                                  float* out) {
    int b = blockIdx.x, mi = blockIdx.y, ns = blockIdx.z, t = threadIdx.x;
    // --- prefetch phase: first half of the slab into registers ---
    const float* p = (mi == 0) ? p0 : (mi == 1 ? p1 : p2);
    const float4* pslab = (const float4*)(p + (size_t)b * N * C + (size_t)ns * 32 * C);
    float4 pref[8];
#pragma unroll
    for (int i = 0; i < 8; i++) pref[i] = pslab[t + 256 * i];
    __shared__ float h1[256];
    __shared__ float h2p[4][64];
    __shared__ float h2[64];
    __shared__ float red[4];
    __shared__ float wjs[3];
    __shared__ float sc[256];
    __shared__ float mks[256];
    __shared__ float thr_s;
    // --- MLP phase ---
    float a1 = b1[mi * 256 + t];
#pragma unroll
    for (int ks = 0; ks < 12; ks++) a1 += h1part[(((size_t)ks * 3 + mi) * B + b) * 256 + t];
    float total = breduce_sum<4>(a1, red, t);
    float mean = total * (1.0f / 256.0f);
    float dv = a1 - mean;
    float vtot = breduce_sum<4>(dv * dv, red, t);
    float var = vtot * (1.0f / 256.0f);
    float x = dv / sqrtf(var + 1e-5f) * lng[mi * 256 + t] + lnb[mi * 256 + t];
    x = 0.5f * x * (1.0f + erff(x * 0.70710678118654752f));
    h1[t] = x;
    __syncthreads();
    {
        int col = t & 63, sl = t >> 6;  // 4 slices of 64
        float a2 = 0.f;
        const float* W2 = w2 + (size_t)mi * 256 * 64 + col;
#pragma unroll 8
        for (int e = sl * 64; e < sl * 64 + 64; e++) a2 += h1[e] * W2[(size_t)e * 64];
        h2p[sl][col] = a2;
    }
    __syncthreads();
    if (t < 64) {
        float a2 = b2[mi * 64 + t];
#pragma unroll
        for (int s2 = 0; s2 < 4; s2++) a2 += h2p[s2][t];
        a2 = 0.5f * a2 * (1.0f + erff(a2 * 0.70710678118654752f));
        h2[t] = a2;
    }
    __syncthreads();
    if (t == 0) {
        float l3[3];
        for (int j = 0; j < 3; j++) {
            float a3 = b3[mi * 3 + j];
            for (int e = 0; e < 64; e++) a3 += h2[e] * w3[((size_t)mi * 64 + e) * 3 + j];
            l3[j] = a3;
        }
        float mx = fmaxf(l3[0], fmaxf(l3[1], l3[2]));
        float e0 = expf(l3[0] - mx), e1 = expf(l3[1] - mx), e2 = expf(l3[2] - mx);
        float inv = 1.0f / (e0 + e1 + e2);
        wjs[0] = e0 * inv; wjs[1] = e1 * inv; wjs[2] = e2 * inv;
    }
    __syncthreads();
    // --- score phase ---
    const float* L = lgt + (size_t)(mi * B + b) * 3 * N;
    float score = 0.f;
    for (int j = 0; j < 3; j++) {
        float v = L[j * N + t];
        float mx = breduce_max<4>(v, red, t);
        float e = expf(v - mx);
        float s = breduce_sum<4>(e, red, t);
        float pr = e / s;
        float tot2 = breduce_sum<4>(pr, red, t);
        float mean2 = tot2 * (1.0f / 256.0f);
        float dv2 = pr - mean2;
        float vtot2 = breduce_sum<4>(dv2 * dv2, red, t);
        float sd = sqrtf(vtot2 * (1.0f / 255.0f)) + 1e-5f;
        float z = dv2 / sd;
        float sg = 1.0f / (1.0f + expf(-z));
        score += wjs[j] * sg;
    }
    sc[t] = score;
    __syncthreads();
    {
        int cl = 0, ce = 0;
        for (int m2 = 0; m2 < N; m2++) {
            float v2 = sc[m2];
            cl += (v2 < score) ? 1 : 0;
            ce += (v2 == score) ? 1 : 0;
        }
        if (cl <= 102 && 102 < cl + ce) thr_s = score;
    }
    __syncthreads();
    float thr = thr_s;
    float mk = 1.0f / (1.0f + expf(-(score - thr) * (1.0f / 0.3f)));
    mks[t] = mk;
    if ((t >> 5) == ns)
        out[(size_t)3 * B * N * C + ((size_t)mi * B + b) * N + t] = mk;
    __syncthreads();
    // --- store phase: prefetched half, then stream the second half ---
    nfloat4* oslab = (nfloat4*)(out + (size_t)mi * B * N * C + (size_t)b * N * C
                                + (size_t)ns * 32 * C);
#pragma unroll
    for (int i = 0; i < 8; i++) {
        int idx = t + 256 * i;
        float mkv = mks[ns * 32 + (idx >> 7)];
        nfloat4 nv;
        nv.x = pref[i].x * mkv; nv.y = pref[i].y * mkv;
        nv.z = pref[i].z * mkv; nv.w = pref[i].w * mkv;
        __builtin_nontemporal_store(nv, oslab + idx);
    }
#pragma unroll
    for (int i = 8; i < 16; i++) {
        int idx = t + 256 * i;
        float4 v = pslab[idx];
        float mkv = mks[ns * 32 + (idx >> 7)];
        nfloat4 nv;
        nv.x = v.x * mkv; nv.y = v.y * mkv; nv.z = v.z * mkv; nv.w = v.w * mkv;
        __builtin_nontemporal_store(nv, oslab + idx);
    }
}

extern "C" void kernel_launch(void* const* d_in, const int* in_sizes, int n_in,
                              void* d_out, int out_size, void* d_ws, size_t ws_size,
                              hipStream_t stream) {
    const float* rgb   = (const float*)d_in[0];
    const float* nir   = (const float*)d_in[1];
    const float* tir   = (const float*)d_in[2];
    const float* rgb_g = (const float*)d_in[3];
    const float* nir_g = (const float*)d_in[4];
    const float* tir_g = (const float*)d_in[5];
    const float* attn_qw = (const float*)d_in[6];
    const float* attn_qb = (const float*)d_in[7];
    const float* attn_kw = (const float*)d_in[8];
    const float* attn_kb = (const float*)d_in[9];
    const float* mlp_w1 = (const float*)d_in[10];
    const float* mlp_b1 = (const float*)d_in[11];
    const float* ln_g = (const float*)d_in[12];
    const float* ln_b = (const float*)d_in[13];
    const float* mlp_w2 = (const float*)d_in[14];
    const float* mlp_b2 = (const float*)d_in[15];
    const float* mlp_w3 = (const float*)d_in[16];
    const float* mlp_b3 = (const float*)d_in[17];
    float* out = (float*)d_out;

    float* ws = (float*)d_ws;
    // layout (floats):
    float* part     = ws;                // 8*294912 = 2359296
    float* kpart    = ws + 2359296;      // 2359296
    float* qkb_part = ws + 4718592;      // 9*8*64 = 4608 -> pad 5120
    float* h1part   = ws + 4723712;      // 12*3*64*256 = 589824
    float* lgt      = ws + 5313536;      // 3*64*3*256 = 147456
    float* gn       = ws + 5460992;      // 3*64*512 = 98304
    // total 5559296 floats = 22.2 MB

    k_proj_mlp<<<723, 256, 0, stream>>>(rgb_g, nir_g, tir_g, attn_qw, mlp_w1,
                                        part, h1part, gn);
    k_kproj<<<dim3(8, 9, 8), 256, 0, stream>>>(attn_kw, part, attn_qb, attn_kb,
                                               kpart, qkb_part);
    k_logits<<<dim3(B, 3, 8), 256, 0, stream>>>(rgb, nir, tir, kpart, qkb_part, gn, lgt);
    k_finscale<<<dim3(B, 3, 8), 256, 0, stream>>>(lgt, h1part, mlp_b1, ln_g, ln_b,
                                                  mlp_w2, mlp_b2, mlp_w3, mlp_b3,
                                                  rgb, nir, tir, out);
}